// Round 3
// baseline (975.204 us; speedup 1.0000x reference)
//
#include <hip/hip_runtime.h>

#define TT 1024
#define SSZ 1024
#define DD 64
#define BHN 64
#define BSZN 4
#define EEN 1024
#define EPSF 1e-6f

// scratch for the gathered attention matrix [T, BSZ, E] = 16 MB (static to avoid ws_size assumptions)
__device__ float g_X[(size_t)TT * BSZN * EEN];

// ---------------- DPP helpers (canonical gfx9 64-lane scan stages) ----------------
template<int CTRL, int RM>
__device__ __forceinline__ float f_dpp(float x, float ident) {
  return __builtin_bit_cast(float,
      __builtin_amdgcn_update_dpp(__builtin_bit_cast(int, ident),
                                  __builtin_bit_cast(int, x),
                                  CTRL, RM, 0xF, false));
}

__device__ __forceinline__ float wscan_add(float x) {
  x += f_dpp<0x111, 0xF>(x, 0.0f);
  x += f_dpp<0x112, 0xF>(x, 0.0f);
  x += f_dpp<0x114, 0xF>(x, 0.0f);
  x += f_dpp<0x118, 0xF>(x, 0.0f);
  x += f_dpp<0x142, 0xA>(x, 0.0f);
  x += f_dpp<0x143, 0xC>(x, 0.0f);
  return x;
}

__device__ __forceinline__ float wave_shr1(float x, float ident) {
  return f_dpp<0x138, 0xF>(x, ident);  // wave_shr:1 (lane0 -> ident)
}

// ---------------- K1: p_choose = sigmoid(Q K^T + bias) -> alpha region ----------------
__global__ __launch_bounds__(256) void k_energy(const float* __restrict__ Q,
                                                const float* __restrict__ Kp,
                                                const float* __restrict__ eb,
                                                float* __restrict__ P) {
  __shared__ float As[64][132];  // [k][m], transposed
  __shared__ float Bs[64][132];  // [k][n], transposed
  const int tid = threadIdx.x;
  const int b = blockIdx.x >> 6;
  const int tile = blockIdx.x & 63;
  const int m0 = (tile >> 3) << 7;
  const int n0 = (tile & 7) << 7;

  {
    const int kc = (tid & 15) << 2;
    const int rr = (tid >> 4) << 2;
    const float* qb = Q + (size_t)b * TT * DD;
    const float* kb = Kp + (size_t)b * SSZ * DD;
#pragma unroll
    for (int pass = 0; pass < 2; ++pass) {
      const int r = rr + (pass << 6);
      float4 a0 = *(const float4*)(qb + (size_t)(m0 + r + 0) * DD + kc);
      float4 a1 = *(const float4*)(qb + (size_t)(m0 + r + 1) * DD + kc);
      float4 a2 = *(const float4*)(qb + (size_t)(m0 + r + 2) * DD + kc);
      float4 a3 = *(const float4*)(qb + (size_t)(m0 + r + 3) * DD + kc);
      *(float4*)&As[kc + 0][r] = make_float4(a0.x, a1.x, a2.x, a3.x);
      *(float4*)&As[kc + 1][r] = make_float4(a0.y, a1.y, a2.y, a3.y);
      *(float4*)&As[kc + 2][r] = make_float4(a0.z, a1.z, a2.z, a3.z);
      *(float4*)&As[kc + 3][r] = make_float4(a0.w, a1.w, a2.w, a3.w);
      float4 b0 = *(const float4*)(kb + (size_t)(n0 + r + 0) * DD + kc);
      float4 b1 = *(const float4*)(kb + (size_t)(n0 + r + 1) * DD + kc);
      float4 b2 = *(const float4*)(kb + (size_t)(n0 + r + 2) * DD + kc);
      float4 b3 = *(const float4*)(kb + (size_t)(n0 + r + 3) * DD + kc);
      *(float4*)&Bs[kc + 0][r] = make_float4(b0.x, b1.x, b2.x, b3.x);
      *(float4*)&Bs[kc + 1][r] = make_float4(b0.y, b1.y, b2.y, b3.y);
      *(float4*)&Bs[kc + 2][r] = make_float4(b0.z, b1.z, b2.z, b3.z);
      *(float4*)&Bs[kc + 3][r] = make_float4(b0.w, b1.w, b2.w, b3.w);
    }
  }
  __syncthreads();

  const int tx = tid & 15, ty = tid >> 4;
  float acc[8][8];
#pragma unroll
  for (int i = 0; i < 8; ++i)
#pragma unroll
    for (int j = 0; j < 8; ++j) acc[i][j] = 0.0f;

#pragma unroll 8
  for (int k = 0; k < 64; ++k) {
    float4 a0 = *(const float4*)&As[k][ty << 3];
    float4 a1 = *(const float4*)&As[k][(ty << 3) + 4];
    float4 b0 = *(const float4*)&Bs[k][tx << 3];
    float4 b1 = *(const float4*)&Bs[k][(tx << 3) + 4];
    float av[8] = {a0.x, a0.y, a0.z, a0.w, a1.x, a1.y, a1.z, a1.w};
    float bv[8] = {b0.x, b0.y, b0.z, b0.w, b1.x, b1.y, b1.z, b1.w};
#pragma unroll
    for (int i = 0; i < 8; ++i)
#pragma unroll
      for (int j = 0; j < 8; ++j) acc[i][j] = fmaf(av[i], bv[j], acc[i][j]);
  }

  const float bias = eb[0];
#pragma unroll
  for (int i = 0; i < 8; ++i) {
    const size_t row = (size_t)b * TT + m0 + (ty << 3) + i;
    float o[8];
#pragma unroll
    for (int j = 0; j < 8; ++j) {
      float x = acc[i][j] + bias;
      o[j] = __builtin_amdgcn_rcpf(1.0f + __expf(-x));  // sigmoid
    }
    float* dst = P + row * SSZ + n0 + (tx << 3);
    *(float4*)dst = make_float4(o[0], o[1], o[2], o[3]);
    *(float4*)(dst + 4) = make_float4(o[4], o[5], o[6], o[7]);
  }
}

// ---------------- K2: 4-wave s-split expected-alignment scan ----------------
// Linear recurrence over s in "E-convention": E passed between segments is
// E = f_last * D_last.  Per wave: A_w = prod of its 256 f's, B_w from local
// chains + DPP wave scan; cross-wave combine via 12 LDS floats. Raw s_barrier
// with lgkmcnt(0) only (NOT __syncthreads -> keeps global prefetch in flight).

// next-row prep: consume q (row f's), reload q <- row TR, rebuild scan state
#define PREP(QS, TR) do {                                                      \
  f0 = 1.0f - (QS).x; f1 = 1.0f - (QS).y; f2 = 1.0f - (QS).z; f3 = 1.0f - (QS).w; \
  { int rr = (TR); if (rr > TT - 1) rr = TT - 1;                               \
    (QS) = *(const float4*)(gb + (size_t)rr * SSZ); }                          \
  l0 = f0; l1 = l0 * f1; l2 = l1 * f2; l3 = l2 * f3;                           \
  As0 = l3;                                                                    \
  As1 = As0 * f_dpp<0x111, 0xF>(As0, 1.0f);                                    \
  As2 = As1 * f_dpp<0x112, 0xF>(As1, 1.0f);                                    \
  As3 = As2 * f_dpp<0x114, 0xF>(As2, 1.0f);                                    \
  As4 = As3 * f_dpp<0x118, 0xF>(As3, 1.0f);                                    \
  As5 = As4 * f_dpp<0x142, 0xA>(As4, 1.0f);                                    \
  { float A6 = As5 * f_dpp<0x143, 0xC>(As5, 1.0f);                             \
    wExcl = wave_shr1(A6, 1.0f);                                               \
    if (lane == 63) ldsA[w] = A6; }                                            \
} while (0)

#define STEP(T, QN) do {                                                       \
  const int t = (T);                                                           \
  /* ---- P1: needs A(t) [LDS], prev ---- */                                   \
  float Av0g = ldsA[0], Av1g = ldsA[1], Av2g = ldsA[2];                        \
  float Pw = 1.0f;                                                             \
  if (w > 0) Pw = Av0g;                                                        \
  if (w > 1) Pw *= Av1g;                                                       \
  if (w > 2) Pw *= Av2g;                                                       \
  float c0 = (Pw * 1e6f) * wExcl;                                              \
  float bb0 = fminf(c0 * prev0, prev0);                                        \
  float bb1 = fminf((c0 * l0) * prev1, prev1);                                 \
  float bb2 = fminf((c0 * l1) * prev2, prev2);                                 \
  float bb3 = fminf((c0 * l2) * prev3, prev3);                                 \
  float Blo0 = bb0;                                                            \
  float Blo1 = fmaf(f0, Blo0, bb1);                                            \
  float Blo2 = fmaf(f1, Blo1, bb2);                                            \
  float Blo3 = fmaf(f2, Blo2, bb3);                                            \
  float B = f3 * Blo3;                                                         \
  B = fmaf(As0, f_dpp<0x111, 0xF>(B, 0.0f), B);                                \
  B = fmaf(As1, f_dpp<0x112, 0xF>(B, 0.0f), B);                                \
  B = fmaf(As2, f_dpp<0x114, 0xF>(B, 0.0f), B);                                \
  B = fmaf(As3, f_dpp<0x118, 0xF>(B, 0.0f), B);                                \
  B = fmaf(As4, f_dpp<0x142, 0xA>(B, 0.0f), B);                                \
  float Bfull = fmaf(As5, f_dpp<0x143, 0xC>(B, 0.0f), B);                      \
  float wB = wave_shr1(Bfull, 0.0f);                                           \
  if (lane == 63) ldsB[w] = Bfull;                                             \
  if ((T) > 0 && tid == 255) { /* residual-fixed store of row t-1 */           \
    float tot = (ldsS[0] + ldsS[1]) + (ldsS[2] + ldsS[3]);                     \
    float rest = tot - pend.w;                                                 \
    pend.w = 1.0f - fminf(fmaxf(rest, 0.0f), 1.0f);                            \
    *(float4*)(gb + (size_t)(t - 1) * SSZ) = pend;                             \
  }                                                                            \
  asm volatile("s_waitcnt lgkmcnt(0)" ::: "memory");                           \
  __builtin_amdgcn_s_barrier();                                                \
  /* ---- P2: needs B(t) [LDS] ---- */                                         \
  float Ew = 0.0f;                                                             \
  { float Bv0 = ldsB[0], Bv1 = ldsB[1], Bv2 = ldsB[2];                         \
    if (w == 1) Ew = Bv0;                                                      \
    else if (w == 2) Ew = fmaf(Av1g, Bv0, Bv1);                                \
    else if (w == 3) Ew = fmaf(Av2g, fmaf(Av1g, Bv0, Bv1), Bv2); }             \
  float El = fmaf(wExcl, Ew, wB);                                              \
  float D0 = Blo0 + El;                                                        \
  float D1 = fmaf(l0, El, Blo1);                                               \
  float D2 = fmaf(l1, El, Blo2);                                               \
  float D3 = fmaf(l2, El, Blo3);                                               \
  float a0 = fminf(fmaf(-f0, D0, D0), 1.0f);                                   \
  float a1 = fminf(fmaf(-f1, D1, D1), 1.0f);                                   \
  float a2 = fminf(fmaf(-f2, D2, D2), 1.0f);                                   \
  float a3 = fminf(fmaf(-f3, D3, D3), 1.0f);                                   \
  prev0 = a0; prev1 = a1; prev2 = a2; prev3 = a3;                              \
  float4 av4 = make_float4(a0, a1, a2, a3);                                    \
  if (tid != 255) *(float4*)(gb + (size_t)t * SSZ) = av4;                      \
  else pend = av4; /* defer: last elem may get residual fix */                 \
  float la = (a0 + a1) + (a2 + a3);                                            \
  float wsum = wscan_add(la);                                                  \
  if (lane == 63) ldsS[w] = wsum;                                              \
  PREP(QN, (T) + 5);                                                           \
  asm volatile("s_waitcnt lgkmcnt(0)" ::: "memory");                           \
  __builtin_amdgcn_s_barrier();                                                \
} while (0)

__global__ __launch_bounds__(256, 1) void k_scan(float* __restrict__ A) {
  const int b = blockIdx.x;
  const int tid = threadIdx.x;
  const int w = tid >> 6;
  const int lane = tid & 63;
  __shared__ float ldsA[4];
  __shared__ float ldsB[4];
  __shared__ float ldsS[4];

  // lane owns s = w*256 + lane*4 .. +3
  float* gb = A + (size_t)b * TT * SSZ + ((size_t)w << 8) + ((size_t)lane << 2);

  float prev0 = 0.0f, prev1 = 0.0f, prev2 = 0.0f, prev3 = 0.0f;
  if (tid == 0) prev0 = 1.0f;
  float4 pend = make_float4(0.f, 0.f, 0.f, 0.f);

  float f0, f1, f2, f3, l0, l1, l2, l3;
  float As0, As1, As2, As3, As4, As5, wExcl;

  // prologue: rows 0..3 into ring, prep row 0, refill slot 0 with row 4
  float4 q0 = *(const float4*)(gb + 0 * SSZ);
  float4 q1 = *(const float4*)(gb + 1 * SSZ);
  float4 q2 = *(const float4*)(gb + 2 * SSZ);
  float4 q3 = *(const float4*)(gb + 3 * SSZ);
  PREP(q0, 4);
  asm volatile("s_waitcnt lgkmcnt(0)" ::: "memory");
  __builtin_amdgcn_s_barrier();

  for (int t0 = 0; t0 < TT; t0 += 4) {
    STEP(t0 + 0, q1);
    STEP(t0 + 1, q2);
    STEP(t0 + 2, q3);
    STEP(t0 + 3, q0);
  }

  // epilogue: residual-fixed store of the final row
  if (tid == 255) {
    float tot = (ldsS[0] + ldsS[1]) + (ldsS[2] + ldsS[3]);
    float rest = tot - pend.w;
    pend.w = 1.0f - fminf(fmaxf(rest, 0.0f), 1.0f);
    *(float4*)(gb + (size_t)(TT - 1) * SSZ) = pend;
  }
}

// ---------------- K3: X[t,bz,h*64+d] = sum_s alpha[bh,t,s] * V[bh,s,d] ----------------
__global__ __launch_bounds__(256) void k_av(const float* __restrict__ Al,
                                            const float* __restrict__ V) {
  __shared__ float As[64][132];  // [k(s)][m(t)] transposed
  __shared__ float Bs[64][64];   // [k(s)][n(d)] natural
  const int tid = threadIdx.x;
  const int bh = blockIdx.x >> 3;
  const int m0 = (blockIdx.x & 7) << 7;
  const int bz = bh >> 4, hh = bh & 15;
  const float* ab = Al + (size_t)bh * TT * SSZ;
  const float* vb = V + (size_t)bh * SSZ * DD;
  const int tx = tid & 15, ty = tid >> 4;

  float acc[8][4];
#pragma unroll
  for (int i = 0; i < 8; ++i)
#pragma unroll
    for (int j = 0; j < 4; ++j) acc[i][j] = 0.0f;

  for (int s0 = 0; s0 < SSZ; s0 += 64) {
    {
      const int kc = (tid & 15) << 2;
      const int rr = (tid >> 4) << 2;
#pragma unroll
      for (int pass = 0; pass < 2; ++pass) {
        const int r = rr + (pass << 6);
        float4 a0 = *(const float4*)(ab + (size_t)(m0 + r + 0) * SSZ + s0 + kc);
        float4 a1 = *(const float4*)(ab + (size_t)(m0 + r + 1) * SSZ + s0 + kc);
        float4 a2 = *(const float4*)(ab + (size_t)(m0 + r + 2) * SSZ + s0 + kc);
        float4 a3 = *(const float4*)(ab + (size_t)(m0 + r + 3) * SSZ + s0 + kc);
        *(float4*)&As[kc + 0][r] = make_float4(a0.x, a1.x, a2.x, a3.x);
        *(float4*)&As[kc + 1][r] = make_float4(a0.y, a1.y, a2.y, a3.y);
        *(float4*)&As[kc + 2][r] = make_float4(a0.z, a1.z, a2.z, a3.z);
        *(float4*)&As[kc + 3][r] = make_float4(a0.w, a1.w, a2.w, a3.w);
      }
#pragma unroll
      for (int pass = 0; pass < 4; ++pass) {
        const int vr = (tid >> 4) + (pass << 4);
        const int vc = (tid & 15) << 2;
        *(float4*)&Bs[vr][vc] = *(const float4*)(vb + (size_t)(s0 + vr) * DD + vc);
      }
    }
    __syncthreads();
#pragma unroll 8
    for (int k = 0; k < 64; ++k) {
      float4 a0 = *(const float4*)&As[k][ty << 3];
      float4 a1 = *(const float4*)&As[k][(ty << 3) + 4];
      float4 b0 = *(const float4*)&Bs[k][tx << 2];
      float av[8] = {a0.x, a0.y, a0.z, a0.w, a1.x, a1.y, a1.z, a1.w};
      float bv[4] = {b0.x, b0.y, b0.z, b0.w};
#pragma unroll
      for (int i = 0; i < 8; ++i)
#pragma unroll
        for (int j = 0; j < 4; ++j) acc[i][j] = fmaf(av[i], bv[j], acc[i][j]);
    }
    __syncthreads();
  }
#pragma unroll
  for (int i = 0; i < 8; ++i) {
    const int t = m0 + (ty << 3) + i;
    float* dst = g_X + ((size_t)t * BSZN + bz) * EEN + hh * DD + (tx << 2);
    *(float4*)dst = make_float4(acc[i][0], acc[i][1], acc[i][2], acc[i][3]);
  }
}

// ---------------- K4: Out = X @ W^T + b ----------------
__global__ __launch_bounds__(256) void k_out(const float* __restrict__ W,
                                             const float* __restrict__ Bb,
                                             float* __restrict__ Out) {
  __shared__ float As[32][132];
  __shared__ float Bs[32][132];
  const int tid = threadIdx.x;
  const int m0 = (blockIdx.x >> 3) << 7;
  const int n0 = (blockIdx.x & 7) << 7;
  const int tx = tid & 15, ty = tid >> 4;
  const int kc = (tid & 7) << 2;
  const int r = (tid >> 3) << 2;

  float acc[8][8];
#pragma unroll
  for (int i = 0; i < 8; ++i)
#pragma unroll
    for (int j = 0; j < 8; ++j) acc[i][j] = 0.0f;

  for (int k0 = 0; k0 < EEN; k0 += 32) {
    {
      float4 x0 = *(const float4*)(g_X + (size_t)(m0 + r + 0) * EEN + k0 + kc);
      float4 x1 = *(const float4*)(g_X + (size_t)(m0 + r + 1) * EEN + k0 + kc);
      float4 x2 = *(const float4*)(g_X + (size_t)(m0 + r + 2) * EEN + k0 + kc);
      float4 x3 = *(const float4*)(g_X + (size_t)(m0 + r + 3) * EEN + k0 + kc);
      *(float4*)&As[kc + 0][r] = make_float4(x0.x, x1.x, x2.x, x3.x);
      *(float4*)&As[kc + 1][r] = make_float4(x0.y, x1.y, x2.y, x3.y);
      *(float4*)&As[kc + 2][r] = make_float4(x0.z, x1.z, x2.z, x3.z);
      *(float4*)&As[kc + 3][r] = make_float4(x0.w, x1.w, x2.w, x3.w);
      float4 w0 = *(const float4*)(W + (size_t)(n0 + r + 0) * EEN + k0 + kc);
      float4 w1 = *(const float4*)(W + (size_t)(n0 + r + 1) * EEN + k0 + kc);
      float4 w2 = *(const float4*)(W + (size_t)(n0 + r + 2) * EEN + k0 + kc);
      float4 w3 = *(const float4*)(W + (size_t)(n0 + r + 3) * EEN + k0 + kc);
      *(float4*)&Bs[kc + 0][r] = make_float4(w0.x, w1.x, w2.x, w3.x);
      *(float4*)&Bs[kc + 1][r] = make_float4(w0.y, w1.y, w2.y, w3.y);
      *(float4*)&Bs[kc + 2][r] = make_float4(w0.z, w1.z, w2.z, w3.z);
      *(float4*)&Bs[kc + 3][r] = make_float4(w0.w, w1.w, w2.w, w3.w);
    }
    __syncthreads();
#pragma unroll 8
    for (int k = 0; k < 32; ++k) {
      float4 a0 = *(const float4*)&As[k][ty << 3];
      float4 a1 = *(const float4*)&As[k][(ty << 3) + 4];
      float4 b0 = *(const float4*)&Bs[k][tx << 3];
      float4 b1 = *(const float4*)&Bs[k][(tx << 3) + 4];
      float av[8] = {a0.x, a0.y, a0.z, a0.w, a1.x, a1.y, a1.z, a1.w};
      float bv[8] = {b0.x, b0.y, b0.z, b0.w, b1.x, b1.y, b1.z, b1.w};
#pragma unroll
      for (int i = 0; i < 8; ++i)
#pragma unroll
        for (int j = 0; j < 8; ++j) acc[i][j] = fmaf(av[i], bv[j], acc[i][j]);
    }
    __syncthreads();
  }

  float4 bb0 = *(const float4*)(Bb + n0 + (tx << 3));
  float4 bb1 = *(const float4*)(Bb + n0 + (tx << 3) + 4);
  float bv[8] = {bb0.x, bb0.y, bb0.z, bb0.w, bb1.x, bb1.y, bb1.z, bb1.w};
#pragma unroll
  for (int i = 0; i < 8; ++i) {
    float o[8];
#pragma unroll
    for (int j = 0; j < 8; ++j) o[j] = acc[i][j] + bv[j];
    float* dst = Out + (size_t)(m0 + (ty << 3) + i) * EEN + n0 + (tx << 3);
    *(float4*)dst = make_float4(o[0], o[1], o[2], o[3]);
    *(float4*)(dst + 4) = make_float4(o[4], o[5], o[6], o[7]);
  }
}

extern "C" void kernel_launch(void* const* d_in, const int* in_sizes, int n_in,
                              void* d_out, int out_size, void* d_ws, size_t ws_size,
                              hipStream_t stream) {
  const float* Q  = (const float*)d_in[0];
  const float* K  = (const float*)d_in[1];
  const float* V  = (const float*)d_in[2];
  const float* W  = (const float*)d_in[3];
  const float* Bb = (const float*)d_in[4];
  const float* eb = (const float*)d_in[5];
  float* Out = (float*)d_out;
  float* Alpha = Out + (size_t)TT * BSZN * EEN;  // output #1 region, also staging for p_choose

  k_energy<<<dim3(BHN * 64), dim3(256), 0, stream>>>(Q, K, eb, Alpha);
  k_scan<<<dim3(BHN), dim3(256), 0, stream>>>(Alpha);
  k_av<<<dim3(BHN * 8), dim3(256), 0, stream>>>(Alpha, V);
  k_out<<<dim3(256), dim3(256), 0, stream>>>(W, Bb, Out);
}

// Round 5
// 819.289 us; speedup vs baseline: 1.1903x; 1.1903x over previous
//
#include <hip/hip_runtime.h>

#define TT 1024
#define SSZ 1024
#define DD 64
#define BHN 64
#define BSZN 4
#define EEN 1024
#define EPSF 1e-6f

typedef float f32x4 __attribute__((ext_vector_type(4)));

// scratch for the gathered attention matrix [T, BSZ, E] = 16 MB (static to avoid ws_size assumptions)
__device__ float g_X[(size_t)TT * BSZN * EEN];

// ---------------- DPP helpers (canonical gfx9 64-lane scan stages) ----------------
template<int CTRL, int RM>
__device__ __forceinline__ float f_dpp(float x, float ident) {
  return __builtin_bit_cast(float,
      __builtin_amdgcn_update_dpp(__builtin_bit_cast(int, ident),
                                  __builtin_bit_cast(int, x),
                                  CTRL, RM, 0xF, false));
}

__device__ __forceinline__ float wscan_add(float x) {
  x += f_dpp<0x111, 0xF>(x, 0.0f);
  x += f_dpp<0x112, 0xF>(x, 0.0f);
  x += f_dpp<0x114, 0xF>(x, 0.0f);
  x += f_dpp<0x118, 0xF>(x, 0.0f);
  x += f_dpp<0x142, 0xA>(x, 0.0f);
  x += f_dpp<0x143, 0xC>(x, 0.0f);
  return x;
}

__device__ __forceinline__ float wave_shr1(float x, float ident) {
  return f_dpp<0x138, 0xF>(x, ident);  // wave_shr:1 (lane0 -> ident)
}

// pinned-in-register async global ops: volatile asm cannot be sunk or DCE'd,
// and all k_scan vmem goes through these -> deterministic vmcnt FIFO counting.
// f32x4 (ext_vector_type) is a true LLVM vector -> binds to a VGPR quad.
__device__ __forceinline__ f32x4 aload(const float* p) {
  f32x4 r;
  asm volatile("global_load_dwordx4 %0, %1, off" : "=v"(r) : "v"(p));
  return r;
}
__device__ __forceinline__ void astore(float* p, f32x4 v) {
  asm volatile("global_store_dwordx4 %0, %1, off" :: "v"(p), "v"(v) : "memory");
}

// ---------------- K1: p_choose = sigmoid(Q K^T + bias) -> alpha region ----------------
__global__ __launch_bounds__(256) void k_energy(const float* __restrict__ Q,
                                                const float* __restrict__ Kp,
                                                const float* __restrict__ eb,
                                                float* __restrict__ P) {
  __shared__ float As[64][132];  // [k][m], transposed
  __shared__ float Bs[64][132];  // [k][n], transposed
  const int tid = threadIdx.x;
  const int b = blockIdx.x >> 6;
  const int tile = blockIdx.x & 63;
  const int m0 = (tile >> 3) << 7;
  const int n0 = (tile & 7) << 7;

  {
    const int kc = (tid & 15) << 2;
    const int rr = (tid >> 4) << 2;
    const float* qb = Q + (size_t)b * TT * DD;
    const float* kb = Kp + (size_t)b * SSZ * DD;
#pragma unroll
    for (int pass = 0; pass < 2; ++pass) {
      const int r = rr + (pass << 6);
      float4 a0 = *(const float4*)(qb + (size_t)(m0 + r + 0) * DD + kc);
      float4 a1 = *(const float4*)(qb + (size_t)(m0 + r + 1) * DD + kc);
      float4 a2 = *(const float4*)(qb + (size_t)(m0 + r + 2) * DD + kc);
      float4 a3 = *(const float4*)(qb + (size_t)(m0 + r + 3) * DD + kc);
      *(float4*)&As[kc + 0][r] = make_float4(a0.x, a1.x, a2.x, a3.x);
      *(float4*)&As[kc + 1][r] = make_float4(a0.y, a1.y, a2.y, a3.y);
      *(float4*)&As[kc + 2][r] = make_float4(a0.z, a1.z, a2.z, a3.z);
      *(float4*)&As[kc + 3][r] = make_float4(a0.w, a1.w, a2.w, a3.w);
      float4 b0 = *(const float4*)(kb + (size_t)(n0 + r + 0) * DD + kc);
      float4 b1 = *(const float4*)(kb + (size_t)(n0 + r + 1) * DD + kc);
      float4 b2 = *(const float4*)(kb + (size_t)(n0 + r + 2) * DD + kc);
      float4 b3 = *(const float4*)(kb + (size_t)(n0 + r + 3) * DD + kc);
      *(float4*)&Bs[kc + 0][r] = make_float4(b0.x, b1.x, b2.x, b3.x);
      *(float4*)&Bs[kc + 1][r] = make_float4(b0.y, b1.y, b2.y, b3.y);
      *(float4*)&Bs[kc + 2][r] = make_float4(b0.z, b1.z, b2.z, b3.z);
      *(float4*)&Bs[kc + 3][r] = make_float4(b0.w, b1.w, b2.w, b3.w);
    }
  }
  __syncthreads();

  const int tx = tid & 15, ty = tid >> 4;
  float acc[8][8];
#pragma unroll
  for (int i = 0; i < 8; ++i)
#pragma unroll
    for (int j = 0; j < 8; ++j) acc[i][j] = 0.0f;

#pragma unroll 8
  for (int k = 0; k < 64; ++k) {
    float4 a0 = *(const float4*)&As[k][ty << 3];
    float4 a1 = *(const float4*)&As[k][(ty << 3) + 4];
    float4 b0 = *(const float4*)&Bs[k][tx << 3];
    float4 b1 = *(const float4*)&Bs[k][(tx << 3) + 4];
    float av[8] = {a0.x, a0.y, a0.z, a0.w, a1.x, a1.y, a1.z, a1.w};
    float bv[8] = {b0.x, b0.y, b0.z, b0.w, b1.x, b1.y, b1.z, b1.w};
#pragma unroll
    for (int i = 0; i < 8; ++i)
#pragma unroll
      for (int j = 0; j < 8; ++j) acc[i][j] = fmaf(av[i], bv[j], acc[i][j]);
  }

  const float bias = eb[0];
#pragma unroll
  for (int i = 0; i < 8; ++i) {
    const size_t row = (size_t)b * TT + m0 + (ty << 3) + i;
    float o[8];
#pragma unroll
    for (int j = 0; j < 8; ++j) {
      float x = acc[i][j] + bias;
      o[j] = __builtin_amdgcn_rcpf(1.0f + __expf(-x));  // sigmoid
    }
    float* dst = P + row * SSZ + n0 + (tx << 3);
    *(float4*)dst = make_float4(o[0], o[1], o[2], o[3]);
    *(float4*)(dst + 4) = make_float4(o[4], o[5], o[6], o[7]);
  }
}

// ---------------- K2: 4-wave s-split scan, 1 barrier/step, asm-pinned prefetch ----------------
// Per step t (wave w owns s in [w*256, w*256+256)):
//  P1: consume q(t+1) from the register ring (vmcnt(4) guarantees it), build next-row
//      p-state (f,l,A-scan); compute B(t) from prev; lane63 publishes (A(t+1), B(t))
//      as one ds_write_b64 into slot[t&1]; lgkmcnt(0); s_barrier.
//  P2: read other waves' (A,B); combine -> El; D; alpha; prev; asm-store row t
//      (tid255 defers its float4: residual fix applied next step via ldsS handoff).
//  Slots double-buffered on t&1 => single barrier per step is WAR-safe.
#define STEP(T, QS) do {                                                       \
  const int t_ = (T);                                                          \
  asm volatile("s_waitcnt vmcnt(4)" ::: "memory");                             \
  __builtin_amdgcn_sched_barrier(0);                                           \
  float fn0 = 1.0f - QS.x, fn1 = 1.0f - QS.y, fn2 = 1.0f - QS.z, fn3 = 1.0f - QS.w; \
  { int rr = t_ + 5; if (rr > TT - 1) rr = TT - 1;                             \
    QS = aload(gq + (size_t)rr * SSZ); }                                       \
  float ln0 = fn0, ln1 = ln0 * fn1, ln2 = ln1 * fn2, ln3 = ln2 * fn3;          \
  float An0 = ln3;                                                             \
  float An1 = An0 * f_dpp<0x111, 0xF>(An0, 1.0f);                              \
  float An2 = An1 * f_dpp<0x112, 0xF>(An1, 1.0f);                              \
  float An3 = An2 * f_dpp<0x114, 0xF>(An2, 1.0f);                              \
  float An4 = An3 * f_dpp<0x118, 0xF>(An3, 1.0f);                              \
  float An5 = An4 * f_dpp<0x142, 0xA>(An4, 1.0f);                              \
  float An6 = An5 * f_dpp<0x143, 0xC>(An5, 1.0f);                              \
  float wEn = wave_shr1(An6, 1.0f);                                            \
  float bb0 = fminf(c0  * prev0, prev0);                                       \
  float bb1 = fminf(cl0 * prev1, prev1);                                       \
  float bb2 = fminf(cl1 * prev2, prev2);                                       \
  float bb3 = fminf(cl2 * prev3, prev3);                                       \
  float Blo1 = fmaf(fc0, bb0, bb1);                                            \
  float Blo2 = fmaf(fc1, Blo1, bb2);                                           \
  float Blo3 = fmaf(fc2, Blo2, bb3);                                           \
  float B_ = fc3 * Blo3;                                                       \
  B_ = fmaf(As0, f_dpp<0x111, 0xF>(B_, 0.0f), B_);                             \
  B_ = fmaf(As1, f_dpp<0x112, 0xF>(B_, 0.0f), B_);                             \
  B_ = fmaf(As2, f_dpp<0x114, 0xF>(B_, 0.0f), B_);                             \
  B_ = fmaf(As3, f_dpp<0x118, 0xF>(B_, 0.0f), B_);                             \
  B_ = fmaf(As4, f_dpp<0x142, 0xA>(B_, 0.0f), B_);                             \
  float Bfull = fmaf(As5, f_dpp<0x143, 0xC>(B_, 0.0f), B_);                    \
  float wB = wave_shr1(Bfull, 0.0f);                                           \
  if (lane == 63) ldsAB[t_ & 1][w] = make_float2(An6, Bfull);                  \
  asm volatile("s_waitcnt lgkmcnt(0)" ::: "memory");                           \
  __builtin_amdgcn_s_barrier();                                                \
  __builtin_amdgcn_sched_barrier(0);                                           \
  float2 ab0 = ldsAB[t_ & 1][0];                                               \
  float2 ab1 = ldsAB[t_ & 1][1];                                               \
  float2 ab2 = ldsAB[t_ & 1][2];                                               \
  float Ew = 0.0f;                                                             \
  if (w == 1) Ew = ab0.y;                                                      \
  else if (w == 2) Ew = fmaf(A1g, ab0.y, ab1.y);                               \
  else if (w == 3) Ew = fmaf(A2g, fmaf(A1g, ab0.y, ab1.y), ab2.y);             \
  float El = fmaf(wE, Ew, wB);                                                 \
  float D0 = bb0 + El;                                                         \
  float D1 = fmaf(lc0, El, Blo1);                                              \
  float D2 = fmaf(lc1, El, Blo2);                                              \
  float D3 = fmaf(lc2, El, Blo3);                                              \
  float a0 = fminf(fmaf(-fc0, D0, D0), 1.0f);                                  \
  float a1 = fminf(fmaf(-fc1, D1, D1), 1.0f);                                  \
  float a2 = fminf(fmaf(-fc2, D2, D2), 1.0f);                                  \
  float a3 = fminf(fmaf(-fc3, D3, D3), 1.0f);                                  \
  prev0 = a0; prev1 = a1; prev2 = a2; prev3 = a3;                              \
  f32x4 av4; av4.x = a0; av4.y = a1; av4.z = a2; av4.w = a3;                   \
  if (tid != 255) astore(gq + (size_t)t_ * SSZ, av4);                          \
  float la = (a0 + a1) + (a2 + a3);                                            \
  float wsum = wscan_add(la);                                                  \
  if (lane == 63 && w < 3) ldsS[t_ & 1][w] = wsum;                             \
  if (tid == 255) {                                                            \
    if (t_ > 0) {                                                              \
      float tot = ldsS[(t_ - 1) & 1][0] + ldsS[(t_ - 1) & 1][1]                \
                + ldsS[(t_ - 1) & 1][2] + wsum_prev;                           \
      float rest = tot - pend.w;                                               \
      pend.w = 1.0f - fminf(fmaxf(rest, 0.0f), 1.0f);                          \
      astore(gq + (size_t)(t_ - 1) * SSZ, pend);                               \
    }                                                                          \
    pend = av4; wsum_prev = wsum;                                              \
  }                                                                            \
  fc0 = fn0; fc1 = fn1; fc2 = fn2; fc3 = fn3;                                  \
  lc0 = ln0; lc1 = ln1; lc2 = ln2;                                             \
  As0 = An0; As1 = An1; As2 = An2; As3 = An3; As4 = An4; As5 = An5;            \
  wE = wEn;                                                                    \
  float Pw_ = 1.0f;                                                            \
  if (w > 0) Pw_ = ab0.x;                                                      \
  if (w > 1) Pw_ *= ab1.x;                                                     \
  if (w > 2) Pw_ *= ab2.x;                                                     \
  c0 = (Pw_ * 1e6f) * wEn;                                                     \
  cl0 = c0 * ln0; cl1 = c0 * ln1; cl2 = c0 * ln2;                              \
  A1g = ab1.x; A2g = ab2.x;                                                    \
} while (0)

__global__ __launch_bounds__(256, 1) void k_scan(float* __restrict__ A) {
  const int b = blockIdx.x;
  const int tid = threadIdx.x;
  const int w = tid >> 6;
  const int lane = tid & 63;
  __shared__ float2 ldsAB[2][4];
  __shared__ float ldsS[2][4];

  float* gq = A + (size_t)b * TT * SSZ + ((size_t)w << 8) + ((size_t)lane << 2);

  // ring: slot k holds row r with r&3==k
  f32x4 q0 = aload(gq + (size_t)0 * SSZ);
  f32x4 q1 = aload(gq + (size_t)1 * SSZ);
  f32x4 q2 = aload(gq + (size_t)2 * SSZ);
  f32x4 q3 = aload(gq + (size_t)3 * SSZ);
  asm volatile("s_waitcnt vmcnt(0)" ::: "memory");
  __builtin_amdgcn_sched_barrier(0);

  // row-0 state
  float fc0 = 1.0f - q0.x, fc1 = 1.0f - q0.y, fc2 = 1.0f - q0.z, fc3 = 1.0f - q0.w;
  q0 = aload(gq + (size_t)4 * SSZ);
  float lc0 = fc0, lc1 = lc0 * fc1, lc2 = lc1 * fc2;
  float lc3 = lc2 * fc3;
  float As0 = lc3;
  float As1 = As0 * f_dpp<0x111, 0xF>(As0, 1.0f);
  float As2 = As1 * f_dpp<0x112, 0xF>(As1, 1.0f);
  float As3 = As2 * f_dpp<0x114, 0xF>(As2, 1.0f);
  float As4 = As3 * f_dpp<0x118, 0xF>(As3, 1.0f);
  float As5 = As4 * f_dpp<0x142, 0xA>(As4, 1.0f);
  float A6  = As5 * f_dpp<0x143, 0xC>(As5, 1.0f);
  float wE = wave_shr1(A6, 1.0f);
  if (lane == 63) ldsAB[1][w] = make_float2(A6, 0.0f);
  asm volatile("s_waitcnt lgkmcnt(0)" ::: "memory");
  __builtin_amdgcn_s_barrier();
  __builtin_amdgcn_sched_barrier(0);
  float2 pab0 = ldsAB[1][0], pab1 = ldsAB[1][1], pab2 = ldsAB[1][2];
  float A1g = pab1.x, A2g = pab2.x;
  float Pw = 1.0f;
  if (w > 0) Pw = pab0.x;
  if (w > 1) Pw *= pab1.x;
  if (w > 2) Pw *= pab2.x;
  float c0 = (Pw * 1e6f) * wE;
  float cl0 = c0 * lc0, cl1 = c0 * lc1, cl2 = c0 * lc2;

  float prev0 = (tid == 0) ? 1.0f : 0.0f;
  float prev1 = 0.0f, prev2 = 0.0f, prev3 = 0.0f;
  f32x4 pend; pend.x = 0.0f; pend.y = 0.0f; pend.z = 0.0f; pend.w = 0.0f;
  float wsum_prev = 0.0f;

  for (int t0 = 0; t0 < TT; t0 += 4) {
    STEP(t0 + 0, q1);
    STEP(t0 + 1, q2);
    STEP(t0 + 2, q3);
    STEP(t0 + 3, q0);
  }

  // final row's residual fix (row TT-1 pend held by tid255)
  asm volatile("s_waitcnt lgkmcnt(0)" ::: "memory");
  __builtin_amdgcn_s_barrier();
  __builtin_amdgcn_sched_barrier(0);
  if (tid == 255) {
    float tot = ldsS[(TT - 1) & 1][0] + ldsS[(TT - 1) & 1][1]
              + ldsS[(TT - 1) & 1][2] + wsum_prev;
    float rest = tot - pend.w;
    pend.w = 1.0f - fminf(fmaxf(rest, 0.0f), 1.0f);
    astore(gq + (size_t)(TT - 1) * SSZ, pend);
  }
}

// ---------------- K3: X[t,bz,h*64+d] = sum_s alpha[bh,t,s] * V[bh,s,d] ----------------
__global__ __launch_bounds__(256) void k_av(const float* __restrict__ Al,
                                            const float* __restrict__ V) {
  __shared__ float As[64][132];  // [k(s)][m(t)] transposed
  __shared__ float Bs[64][64];   // [k(s)][n(d)] natural
  const int tid = threadIdx.x;
  const int bh = blockIdx.x >> 3;
  const int m0 = (blockIdx.x & 7) << 7;
  const int bz = bh >> 4, hh = bh & 15;
  const float* ab = Al + (size_t)bh * TT * SSZ;
  const float* vb = V + (size_t)bh * SSZ * DD;
  const int tx = tid & 15, ty = tid >> 4;

  float acc[8][4];
#pragma unroll
  for (int i = 0; i < 8; ++i)
#pragma unroll
    for (int j = 0; j < 4; ++j) acc[i][j] = 0.0f;

  for (int s0 = 0; s0 < SSZ; s0 += 64) {
    {
      const int kc = (tid & 15) << 2;
      const int rr = (tid >> 4) << 2;
#pragma unroll
      for (int pass = 0; pass < 2; ++pass) {
        const int r = rr + (pass << 6);
        float4 a0 = *(const float4*)(ab + (size_t)(m0 + r + 0) * SSZ + s0 + kc);
        float4 a1 = *(const float4*)(ab + (size_t)(m0 + r + 1) * SSZ + s0 + kc);
        float4 a2 = *(const float4*)(ab + (size_t)(m0 + r + 2) * SSZ + s0 + kc);
        float4 a3 = *(const float4*)(ab + (size_t)(m0 + r + 3) * SSZ + s0 + kc);
        *(float4*)&As[kc + 0][r] = make_float4(a0.x, a1.x, a2.x, a3.x);
        *(float4*)&As[kc + 1][r] = make_float4(a0.y, a1.y, a2.y, a3.y);
        *(float4*)&As[kc + 2][r] = make_float4(a0.z, a1.z, a2.z, a3.z);
        *(float4*)&As[kc + 3][r] = make_float4(a0.w, a1.w, a2.w, a3.w);
      }
#pragma unroll
      for (int pass = 0; pass < 4; ++pass) {
        const int vr = (tid >> 4) + (pass << 4);
        const int vc = (tid & 15) << 2;
        *(float4*)&Bs[vr][vc] = *(const float4*)(vb + (size_t)(s0 + vr) * DD + vc);
      }
    }
    __syncthreads();
#pragma unroll 8
    for (int k = 0; k < 64; ++k) {
      float4 a0 = *(const float4*)&As[k][ty << 3];
      float4 a1 = *(const float4*)&As[k][(ty << 3) + 4];
      float4 b0 = *(const float4*)&Bs[k][tx << 2];
      float av[8] = {a0.x, a0.y, a0.z, a0.w, a1.x, a1.y, a1.z, a1.w};
      float bv[4] = {b0.x, b0.y, b0.z, b0.w};
#pragma unroll
      for (int i = 0; i < 8; ++i)
#pragma unroll
        for (int j = 0; j < 4; ++j) acc[i][j] = fmaf(av[i], bv[j], acc[i][j]);
    }
    __syncthreads();
  }
#pragma unroll
  for (int i = 0; i < 8; ++i) {
    const int t = m0 + (ty << 3) + i;
    float* dst = g_X + ((size_t)t * BSZN + bz) * EEN + hh * DD + (tx << 2);
    *(float4*)dst = make_float4(acc[i][0], acc[i][1], acc[i][2], acc[i][3]);
  }
}

// ---------------- K4: Out = X @ W^T + b ----------------
__global__ __launch_bounds__(256) void k_out(const float* __restrict__ W,
                                             const float* __restrict__ Bb,
                                             float* __restrict__ Out) {
  __shared__ float As[32][132];
  __shared__ float Bs[32][132];
  const int tid = threadIdx.x;
  const int m0 = (blockIdx.x >> 3) << 7;
  const int n0 = (blockIdx.x & 7) << 7;
  const int tx = tid & 15, ty = tid >> 4;
  const int kc = (tid & 7) << 2;
  const int r = (tid >> 3) << 2;

  float acc[8][8];
#pragma unroll
  for (int i = 0; i < 8; ++i)
#pragma unroll
    for (int j = 0; j < 8; ++j) acc[i][j] = 0.0f;

  for (int k0 = 0; k0 < EEN; k0 += 32) {
    {
      float4 x0 = *(const float4*)(g_X + (size_t)(m0 + r + 0) * EEN + k0 + kc);
      float4 x1 = *(const float4*)(g_X + (size_t)(m0 + r + 1) * EEN + k0 + kc);
      float4 x2 = *(const float4*)(g_X + (size_t)(m0 + r + 2) * EEN + k0 + kc);
      float4 x3 = *(const float4*)(g_X + (size_t)(m0 + r + 3) * EEN + k0 + kc);
      *(float4*)&As[kc + 0][r] = make_float4(x0.x, x1.x, x2.x, x3.x);
      *(float4*)&As[kc + 1][r] = make_float4(x0.y, x1.y, x2.y, x3.y);
      *(float4*)&As[kc + 2][r] = make_float4(x0.z, x1.z, x2.z, x3.z);
      *(float4*)&As[kc + 3][r] = make_float4(x0.w, x1.w, x2.w, x3.w);
      float4 w0 = *(const float4*)(W + (size_t)(n0 + r + 0) * EEN + k0 + kc);
      float4 w1 = *(const float4*)(W + (size_t)(n0 + r + 1) * EEN + k0 + kc);
      float4 w2 = *(const float4*)(W + (size_t)(n0 + r + 2) * EEN + k0 + kc);
      float4 w3 = *(const float4*)(W + (size_t)(n0 + r + 3) * EEN + k0 + kc);
      *(float4*)&Bs[kc + 0][r] = make_float4(w0.x, w1.x, w2.x, w3.x);
      *(float4*)&Bs[kc + 1][r] = make_float4(w0.y, w1.y, w2.y, w3.y);
      *(float4*)&Bs[kc + 2][r] = make_float4(w0.z, w1.z, w2.z, w3.z);
      *(float4*)&Bs[kc + 3][r] = make_float4(w0.w, w1.w, w2.w, w3.w);
    }
    __syncthreads();
#pragma unroll 8
    for (int k = 0; k < 32; ++k) {
      float4 a0 = *(const float4*)&As[k][ty << 3];
      float4 a1 = *(const float4*)&As[k][(ty << 3) + 4];
      float4 b0 = *(const float4*)&Bs[k][tx << 3];
      float4 b1 = *(const float4*)&Bs[k][(tx << 3) + 4];
      float av[8] = {a0.x, a0.y, a0.z, a0.w, a1.x, a1.y, a1.z, a1.w};
      float bv[8] = {b0.x, b0.y, b0.z, b0.w, b1.x, b1.y, b1.z, b1.w};
#pragma unroll
      for (int i = 0; i < 8; ++i)
#pragma unroll
        for (int j = 0; j < 8; ++j) acc[i][j] = fmaf(av[i], bv[j], acc[i][j]);
    }
    __syncthreads();
  }

  float4 bb0 = *(const float4*)(Bb + n0 + (tx << 3));
  float4 bb1 = *(const float4*)(Bb + n0 + (tx << 3) + 4);
  float bv[8] = {bb0.x, bb0.y, bb0.z, bb0.w, bb1.x, bb1.y, bb1.z, bb1.w};
#pragma unroll
  for (int i = 0; i < 8; ++i) {
    float o[8];
#pragma unroll
    for (int j = 0; j < 8; ++j) o[j] = acc[i][j] + bv[j];
    float* dst = Out + (size_t)(m0 + (ty << 3) + i) * EEN + n0 + (tx << 3);
    *(float4*)dst = make_float4(o[0], o[1], o[2], o[3]);
    *(float4*)(dst + 4) = make_float4(o[4], o[5], o[6], o[7]);
  }
}

extern "C" void kernel_launch(void* const* d_in, const int* in_sizes, int n_in,
                              void* d_out, int out_size, void* d_ws, size_t ws_size,
                              hipStream_t stream) {
  const float* Q  = (const float*)d_in[0];
  const float* K  = (const float*)d_in[1];
  const float* V  = (const float*)d_in[2];
  const float* W  = (const float*)d_in[3];
  const float* Bb = (const float*)d_in[4];
  const float* eb = (const float*)d_in[5];
  float* Out = (float*)d_out;
  float* Alpha = Out + (size_t)TT * BSZN * EEN;  // output #1 region, also staging for p_choose

  k_energy<<<dim3(BHN * 64), dim3(256), 0, stream>>>(Q, K, eb, Alpha);
  k_scan<<<dim3(BHN), dim3(256), 0, stream>>>(Alpha);
  k_av<<<dim3(BHN * 8), dim3(256), 0, stream>>>(Alpha, V);
  k_out<<<dim3(256), dim3(256), 0, stream>>>(W, Bb, Out);
}

// Round 6
// 779.279 us; speedup vs baseline: 1.2514x; 1.0513x over previous
//
#include <hip/hip_runtime.h>

#define TT 1024
#define SSZ 1024
#define DD 64
#define BHN 64
#define BSZN 4
#define EEN 1024
#define EPSF 1e-6f

using f32x4 = __attribute__((ext_vector_type(4))) float;
using i32x2 = __attribute__((ext_vector_type(2))) int;
using i32x4 = __attribute__((ext_vector_type(4))) int;
using s16x8 = __attribute__((ext_vector_type(8))) short;

// static buffers (avoid ws_size assumptions)
__device__ unsigned short g_Pb[(size_t)BHN * TT * SSZ];  // bf16 alpha copy (134MB)
__device__ unsigned short g_Vt[(size_t)BHN * DD * SSZ];  // bf16 V^T [bh][d][s] (8MB)
__device__ unsigned short g_Wb[(size_t)EEN * EEN];       // bf16 W [n][k] (2MB)
__device__ unsigned short g_Xb[(size_t)TT * BSZN * EEN]; // bf16 X [t][bz][e] (8MB)

// ---------------- helpers ----------------
template<int CTRL, int RM>
__device__ __forceinline__ float f_dpp(float x, float ident) {
  return __builtin_bit_cast(float,
      __builtin_amdgcn_update_dpp(__builtin_bit_cast(int, ident),
                                  __builtin_bit_cast(int, x),
                                  CTRL, RM, 0xF, false));
}

__device__ __forceinline__ float wscan_add(float x) {
  x += f_dpp<0x111, 0xF>(x, 0.0f);
  x += f_dpp<0x112, 0xF>(x, 0.0f);
  x += f_dpp<0x114, 0xF>(x, 0.0f);
  x += f_dpp<0x118, 0xF>(x, 0.0f);
  x += f_dpp<0x142, 0xA>(x, 0.0f);
  x += f_dpp<0x143, 0xC>(x, 0.0f);
  return x;
}

__device__ __forceinline__ float wave_shr1(float x, float ident) {
  return f_dpp<0x138, 0xF>(x, ident);
}

__device__ __forceinline__ f32x4 aload(const float* p) {
  f32x4 r;
  asm volatile("global_load_dwordx4 %0, %1, off" : "=v"(r) : "v"(p));
  return r;
}
__device__ __forceinline__ void astore(float* p, f32x4 v) {
  asm volatile("global_store_dwordx4 %0, %1, off" :: "v"(p), "v"(v) : "memory");
}
__device__ __forceinline__ void astore2(unsigned short* p, i32x2 v) {
  asm volatile("global_store_dwordx2 %0, %1, off" :: "v"(p), "v"(v) : "memory");
}

__device__ __forceinline__ int cvt_pk(float lo, float hi) {
  int r;
  asm("v_cvt_pk_bf16_f32 %0, %1, %2" : "=v"(r) : "v"(lo), "v"(hi));
  return r;
}
__device__ __forceinline__ unsigned short bfr(float x) {  // scalar RTNE bf16
  unsigned u = __builtin_bit_cast(unsigned, x);
  u += 0x7fffu + ((u >> 16) & 1u);
  return (unsigned short)(u >> 16);
}
__device__ __forceinline__ s16x8 pack8p(const float* p) {  // 8 consecutive f32 -> bf16x8
  f32x4 a = *(const f32x4*)p;
  f32x4 b = *(const f32x4*)(p + 4);
  i32x4 r;
  r[0] = cvt_pk(a[0], a[1]); r[1] = cvt_pk(a[2], a[3]);
  r[2] = cvt_pk(b[0], b[1]); r[3] = cvt_pk(b[2], b[3]);
  return __builtin_bit_cast(s16x8, r);
}
__device__ __forceinline__ s16x8 pack8f(float v0, float v1, float v2, float v3,
                                        float v4, float v5, float v6, float v7) {
  i32x4 r;
  r[0] = cvt_pk(v0, v1); r[1] = cvt_pk(v2, v3);
  r[2] = cvt_pk(v4, v5); r[3] = cvt_pk(v6, v7);
  return __builtin_bit_cast(s16x8, r);
}

// ---------------- prep: W -> bf16 ----------------
__global__ __launch_bounds__(256) void k_prep_w(const float* __restrict__ W) {
  const size_t idx = ((size_t)blockIdx.x * 256 + threadIdx.x) * 8;
  *(s16x8*)(g_Wb + idx) = pack8p(W + idx);
}

// ---------------- prep: V -> bf16 transposed V^T[bh][d][s] ----------------
__global__ __launch_bounds__(256) void k_prep_v(const float* __restrict__ V) {
  __shared__ float tile[64][65];
  const int tid = threadIdx.x;
  const int bh = blockIdx.x >> 4;
  const int s0 = (blockIdx.x & 15) << 6;
  {
    const int r = tid >> 2, cq = (tid & 3) << 4;
    const float* src = V + ((size_t)bh * SSZ + s0 + r) * DD + cq;
    *(float4*)&tile[r][cq + 0]  = *(const float4*)(src + 0);
    *(float4*)&tile[r][cq + 4]  = *(const float4*)(src + 4);
    *(float4*)&tile[r][cq + 8]  = *(const float4*)(src + 8);
    *(float4*)&tile[r][cq + 12] = *(const float4*)(src + 12);
  }
  __syncthreads();
  {
    const int d = tid >> 2, sq = (tid & 3) << 4;
    unsigned short* dst = g_Vt + ((size_t)bh * DD + d) * SSZ + s0 + sq;
    *(s16x8*)(dst + 0) = pack8f(tile[sq + 0][d], tile[sq + 1][d], tile[sq + 2][d], tile[sq + 3][d],
                                tile[sq + 4][d], tile[sq + 5][d], tile[sq + 6][d], tile[sq + 7][d]);
    *(s16x8*)(dst + 8) = pack8f(tile[sq + 8][d], tile[sq + 9][d], tile[sq + 10][d], tile[sq + 11][d],
                                tile[sq + 12][d], tile[sq + 13][d], tile[sq + 14][d], tile[sq + 15][d]);
  }
}

// ---------------- K1: p = sigmoid(Q K^T + bias) via bf16 MFMA ----------------
// wave computes 64x64 tile; A/B frags use identical slot->k map (permutation-safe).
__global__ __launch_bounds__(256) void k_energy(const float* __restrict__ Q,
                                                const float* __restrict__ Kp,
                                                const float* __restrict__ eb,
                                                float* __restrict__ P) {
  const int tid = threadIdx.x, w = tid >> 6, l = tid & 63;
  const int rl = l & 15, kg = l >> 4;
  const int bh = blockIdx.x >> 6;
  const int tile = blockIdx.x & 63;
  const int m0 = (tile >> 2) << 6;
  const int n0 = (((tile & 3) << 2) + w) << 6;
  const float* qb = Q + (size_t)bh * TT * DD;
  const float* kb = Kp + (size_t)bh * SSZ * DD;

  f32x4 acc[4][4];
#pragma unroll
  for (int i = 0; i < 4; ++i)
#pragma unroll
    for (int j = 0; j < 4; ++j) acc[i][j] = (f32x4)0.0f;

#pragma unroll
  for (int ks = 0; ks < 2; ++ks) {
    const int kof = (ks << 5) + (kg << 3);
    s16x8 af[4], bf[4];
#pragma unroll
    for (int fi = 0; fi < 4; ++fi)
      af[fi] = pack8p(qb + (size_t)(m0 + fi * 16 + rl) * DD + kof);
#pragma unroll
    for (int fj = 0; fj < 4; ++fj)
      bf[fj] = pack8p(kb + (size_t)(n0 + fj * 16 + rl) * DD + kof);
#pragma unroll
    for (int fi = 0; fi < 4; ++fi)
#pragma unroll
      for (int fj = 0; fj < 4; ++fj)
        acc[fi][fj] = __builtin_amdgcn_mfma_f32_16x16x32_bf16(af[fi], bf[fj], acc[fi][fj], 0, 0, 0);
  }

  const float bias = eb[0];
  float* pb = P + (size_t)bh * TT * SSZ;
#pragma unroll
  for (int fi = 0; fi < 4; ++fi)
#pragma unroll
    for (int r = 0; r < 4; ++r) {
      const size_t rowoff = (size_t)(m0 + fi * 16 + (kg << 2) + r) * SSZ;
#pragma unroll
      for (int fj = 0; fj < 4; ++fj) {
        float x = acc[fi][fj][r] + bias;
        pb[rowoff + n0 + fj * 16 + rl] = __builtin_amdgcn_rcpf(1.0f + __expf(-x));
      }
    }
}

// ---------------- K2: 4-wave s-split scan (r5 structure) + bf16 alpha copy ----------------
#define STEP(T, QS) do {                                                       \
  const int t_ = (T);                                                          \
  asm volatile("s_waitcnt vmcnt(8)" ::: "memory");                             \
  __builtin_amdgcn_sched_barrier(0);                                           \
  float fn0 = 1.0f - QS.x, fn1 = 1.0f - QS.y, fn2 = 1.0f - QS.z, fn3 = 1.0f - QS.w; \
  { int rr = t_ + 5; if (rr > TT - 1) rr = TT - 1;                             \
    QS = aload(gq + (size_t)rr * SSZ); }                                       \
  float ln0 = fn0, ln1 = ln0 * fn1, ln2 = ln1 * fn2, ln3 = ln2 * fn3;          \
  float An0 = ln3;                                                             \
  float An1 = An0 * f_dpp<0x111, 0xF>(An0, 1.0f);                              \
  float An2 = An1 * f_dpp<0x112, 0xF>(An1, 1.0f);                              \
  float An3 = An2 * f_dpp<0x114, 0xF>(An2, 1.0f);                              \
  float An4 = An3 * f_dpp<0x118, 0xF>(An3, 1.0f);                              \
  float An5 = An4 * f_dpp<0x142, 0xA>(An4, 1.0f);                              \
  float An6 = An5 * f_dpp<0x143, 0xC>(An5, 1.0f);                              \
  float wEn = wave_shr1(An6, 1.0f);                                            \
  float bb0 = fminf(c0  * prev0, prev0);                                       \
  float bb1 = fminf(cl0 * prev1, prev1);                                       \
  float bb2 = fminf(cl1 * prev2, prev2);                                       \
  float bb3 = fminf(cl2 * prev3, prev3);                                       \
  float Blo1 = fmaf(fc0, bb0, bb1);                                            \
  float Blo2 = fmaf(fc1, Blo1, bb2);                                           \
  float Blo3 = fmaf(fc2, Blo2, bb3);                                           \
  float B_ = fc3 * Blo3;                                                       \
  B_ = fmaf(As0, f_dpp<0x111, 0xF>(B_, 0.0f), B_);                             \
  B_ = fmaf(As1, f_dpp<0x112, 0xF>(B_, 0.0f), B_);                             \
  B_ = fmaf(As2, f_dpp<0x114, 0xF>(B_, 0.0f), B_);                             \
  B_ = fmaf(As3, f_dpp<0x118, 0xF>(B_, 0.0f), B_);                             \
  B_ = fmaf(As4, f_dpp<0x142, 0xA>(B_, 0.0f), B_);                             \
  float Bfull = fmaf(As5, f_dpp<0x143, 0xC>(B_, 0.0f), B_);                    \
  float wB = wave_shr1(Bfull, 0.0f);                                           \
  if (lane == 63) ldsAB[t_ & 1][w] = make_float2(An6, Bfull);                  \
  asm volatile("s_waitcnt lgkmcnt(0)" ::: "memory");                           \
  __builtin_amdgcn_s_barrier();                                                \
  __builtin_amdgcn_sched_barrier(0);                                           \
  float2 ab0 = ldsAB[t_ & 1][0];                                               \
  float2 ab1 = ldsAB[t_ & 1][1];                                               \
  float2 ab2 = ldsAB[t_ & 1][2];                                               \
  float Ew = 0.0f;                                                             \
  if (w == 1) Ew = ab0.y;                                                      \
  else if (w == 2) Ew = fmaf(A1g, ab0.y, ab1.y);                               \
  else if (w == 3) Ew = fmaf(A2g, fmaf(A1g, ab0.y, ab1.y), ab2.y);             \
  float El = fmaf(wE, Ew, wB);                                                 \
  float D0 = bb0 + El;                                                         \
  float D1 = fmaf(lc0, El, Blo1);                                              \
  float D2 = fmaf(lc1, El, Blo2);                                              \
  float D3 = fmaf(lc2, El, Blo3);                                              \
  float a0 = fminf(fmaf(-fc0, D0, D0), 1.0f);                                  \
  float a1 = fminf(fmaf(-fc1, D1, D1), 1.0f);                                  \
  float a2 = fminf(fmaf(-fc2, D2, D2), 1.0f);                                  \
  float a3 = fminf(fmaf(-fc3, D3, D3), 1.0f);                                  \
  prev0 = a0; prev1 = a1; prev2 = a2; prev3 = a3;                              \
  f32x4 av4; av4.x = a0; av4.y = a1; av4.z = a2; av4.w = a3;                   \
  if (tid != 255) {                                                            \
    astore(gq + (size_t)t_ * SSZ, av4);                                        \
    i32x2 pk; pk[0] = cvt_pk(a0, a1); pk[1] = cvt_pk(a2, a3);                  \
    astore2(gpb + (size_t)t_ * SSZ, pk);                                       \
  }                                                                            \
  float la = (a0 + a1) + (a2 + a3);                                            \
  float wsum = wscan_add(la);                                                  \
  if (lane == 63 && w < 3) ldsS[t_ & 1][w] = wsum;                             \
  if (tid == 255) {                                                            \
    if (t_ > 0) {                                                              \
      float tot = ldsS[(t_ - 1) & 1][0] + ldsS[(t_ - 1) & 1][1]                \
                + ldsS[(t_ - 1) & 1][2] + wsum_prev;                           \
      float rest = tot - pend.w;                                               \
      pend.w = 1.0f - fminf(fmaxf(rest, 0.0f), 1.0f);                          \
      astore(gq + (size_t)(t_ - 1) * SSZ, pend);                               \
      i32x2 pk2; pk2[0] = cvt_pk(pend.x, pend.y); pk2[1] = cvt_pk(pend.z, pend.w); \
      astore2(gpb + (size_t)(t_ - 1) * SSZ, pk2);                              \
    }                                                                          \
    pend = av4; wsum_prev = wsum;                                              \
  }                                                                            \
  fc0 = fn0; fc1 = fn1; fc2 = fn2; fc3 = fn3;                                  \
  lc0 = ln0; lc1 = ln1; lc2 = ln2;                                             \
  As0 = An0; As1 = An1; As2 = An2; As3 = An3; As4 = An4; As5 = An5;            \
  wE = wEn;                                                                    \
  float Pw_ = 1.0f;                                                            \
  if (w > 0) Pw_ = ab0.x;                                                      \
  if (w > 1) Pw_ *= ab1.x;                                                     \
  if (w > 2) Pw_ *= ab2.x;                                                     \
  c0 = (Pw_ * 1e6f) * wEn;                                                     \
  cl0 = c0 * ln0; cl1 = c0 * ln1; cl2 = c0 * ln2;                              \
  A1g = ab1.x; A2g = ab2.x;                                                    \
} while (0)

__global__ __launch_bounds__(256, 1) void k_scan(float* __restrict__ A) {
  const int b = blockIdx.x;
  const int tid = threadIdx.x;
  const int w = tid >> 6;
  const int lane = tid & 63;
  __shared__ float2 ldsAB[2][4];
  __shared__ float ldsS[2][4];

  float* gq = A + (size_t)b * TT * SSZ + ((size_t)w << 8) + ((size_t)lane << 2);
  unsigned short* gpb = g_Pb + (size_t)b * TT * SSZ + ((size_t)w << 8) + ((size_t)lane << 2);

  f32x4 q0 = aload(gq + (size_t)0 * SSZ);
  f32x4 q1 = aload(gq + (size_t)1 * SSZ);
  f32x4 q2 = aload(gq + (size_t)2 * SSZ);
  f32x4 q3 = aload(gq + (size_t)3 * SSZ);
  asm volatile("s_waitcnt vmcnt(0)" ::: "memory");
  __builtin_amdgcn_sched_barrier(0);

  float fc0 = 1.0f - q0.x, fc1 = 1.0f - q0.y, fc2 = 1.0f - q0.z, fc3 = 1.0f - q0.w;
  q0 = aload(gq + (size_t)4 * SSZ);
  float lc0 = fc0, lc1 = lc0 * fc1, lc2 = lc1 * fc2;
  float lc3 = lc2 * fc3;
  float As0 = lc3;
  float As1 = As0 * f_dpp<0x111, 0xF>(As0, 1.0f);
  float As2 = As1 * f_dpp<0x112, 0xF>(As1, 1.0f);
  float As3 = As2 * f_dpp<0x114, 0xF>(As2, 1.0f);
  float As4 = As3 * f_dpp<0x118, 0xF>(As3, 1.0f);
  float As5 = As4 * f_dpp<0x142, 0xA>(As4, 1.0f);
  float A6  = As5 * f_dpp<0x143, 0xC>(As5, 1.0f);
  float wE = wave_shr1(A6, 1.0f);
  if (lane == 63) ldsAB[1][w] = make_float2(A6, 0.0f);
  asm volatile("s_waitcnt lgkmcnt(0)" ::: "memory");
  __builtin_amdgcn_s_barrier();
  __builtin_amdgcn_sched_barrier(0);
  float2 pab0 = ldsAB[1][0], pab1 = ldsAB[1][1], pab2 = ldsAB[1][2];
  float A1g = pab1.x, A2g = pab2.x;
  float Pw = 1.0f;
  if (w > 0) Pw = pab0.x;
  if (w > 1) Pw *= pab1.x;
  if (w > 2) Pw *= pab2.x;
  float c0 = (Pw * 1e6f) * wE;
  float cl0 = c0 * lc0, cl1 = c0 * lc1, cl2 = c0 * lc2;

  float prev0 = (tid == 0) ? 1.0f : 0.0f;
  float prev1 = 0.0f, prev2 = 0.0f, prev3 = 0.0f;
  f32x4 pend; pend.x = 0.0f; pend.y = 0.0f; pend.z = 0.0f; pend.w = 0.0f;
  float wsum_prev = 0.0f;

  for (int t0 = 0; t0 < TT; t0 += 4) {
    STEP(t0 + 0, q1);
    STEP(t0 + 1, q2);
    STEP(t0 + 2, q3);
    STEP(t0 + 3, q0);
  }

  asm volatile("s_waitcnt lgkmcnt(0)" ::: "memory");
  __builtin_amdgcn_s_barrier();
  __builtin_amdgcn_sched_barrier(0);
  if (tid == 255) {
    float tot = ldsS[(TT - 1) & 1][0] + ldsS[(TT - 1) & 1][1]
              + ldsS[(TT - 1) & 1][2] + wsum_prev;
    float rest = tot - pend.w;
    pend.w = 1.0f - fminf(fmaxf(rest, 0.0f), 1.0f);
    astore(gq + (size_t)(TT - 1) * SSZ, pend);
    i32x2 pk; pk[0] = cvt_pk(pend.x, pend.y); pk[1] = cvt_pk(pend.z, pend.w);
    astore2(gpb + (size_t)(TT - 1) * SSZ, pk);
  }
}

// ---------------- K3: X = alpha_bf16 @ V^T_bf16 via MFMA -> g_Xb ----------------
// wave: 16 t-rows x 64 d-cols, K=1024 in 32 steps. grid 1024 blocks x 4 waves.
__global__ __launch_bounds__(256) void k_av() {
  const int tid = threadIdx.x, w = tid >> 6, l = tid & 63;
  const int rl = l & 15, kg = l >> 4;
  const int gw = blockIdx.x * 4 + w;
  const int bh = gw >> 6;
  const int t0 = (gw & 63) << 4;

  const unsigned short* ab = g_Pb + ((size_t)bh * TT + t0 + rl) * SSZ;
  const unsigned short* vb = g_Vt + (size_t)bh * DD * SSZ;

  f32x4 acc[4];
#pragma unroll
  for (int j = 0; j < 4; ++j) acc[j] = (f32x4)0.0f;

  for (int kk = 0; kk < 32; ++kk) {
    const int kof = (kk << 5) + (kg << 3);
    s16x8 a = *(const s16x8*)(ab + kof);
#pragma unroll
    for (int fj = 0; fj < 4; ++fj) {
      s16x8 b = *(const s16x8*)(vb + (size_t)(fj * 16 + rl) * SSZ + kof);
      acc[fj] = __builtin_amdgcn_mfma_f32_16x16x32_bf16(a, b, acc[fj], 0, 0, 0);
    }
  }

  const int bz = bh >> 4, hh = bh & 15;
#pragma unroll
  for (int fj = 0; fj < 4; ++fj) {
    const int d = fj * 16 + rl;
#pragma unroll
    for (int r = 0; r < 4; ++r) {
      const int t = t0 + (kg << 2) + r;
      g_Xb[((size_t)t * BSZN + bz) * EEN + hh * DD + d] = bfr(acc[fj][r]);
    }
  }
}

// ---------------- K4: Out = X_bf16 @ W_bf16^T + b via MFMA ----------------
// wave: 16 m-rows x 64 n-cols, K=1024 in 32 steps. grid 1024 blocks x 4 waves.
__global__ __launch_bounds__(256) void k_out(const float* __restrict__ Bb,
                                             float* __restrict__ Out) {
  const int tid = threadIdx.x, w = tid >> 6, l = tid & 63;
  const int rl = l & 15, kg = l >> 4;
  const int gw = blockIdx.x * 4 + w;
  const int m0 = (gw >> 4) << 4;
  const int n0 = (gw & 15) << 6;

  const unsigned short* xb = g_Xb + (size_t)(m0 + rl) * EEN;

  f32x4 acc[4];
#pragma unroll
  for (int j = 0; j < 4; ++j) acc[j] = (f32x4)0.0f;

  for (int kk = 0; kk < 32; ++kk) {
    const int kof = (kk << 5) + (kg << 3);
    s16x8 a = *(const s16x8*)(xb + kof);
#pragma unroll
    for (int fj = 0; fj < 4; ++fj) {
      s16x8 b = *(const s16x8*)(g_Wb + (size_t)(n0 + fj * 16 + rl) * EEN + kof);
      acc[fj] = __builtin_amdgcn_mfma_f32_16x16x32_bf16(a, b, acc[fj], 0, 0, 0);
    }
  }

#pragma unroll
  for (int fj = 0; fj < 4; ++fj) {
    const float bias = Bb[n0 + fj * 16 + rl];
#pragma unroll
    for (int r = 0; r < 4; ++r) {
      const int m = m0 + (kg << 2) + r;
      Out[(size_t)m * EEN + n0 + fj * 16 + rl] = acc[fj][r] + bias;
    }
  }
}

extern "C" void kernel_launch(void* const* d_in, const int* in_sizes, int n_in,
                              void* d_out, int out_size, void* d_ws, size_t ws_size,
                              hipStream_t stream) {
  const float* Q  = (const float*)d_in[0];
  const float* K  = (const float*)d_in[1];
  const float* V  = (const float*)d_in[2];
  const float* W  = (const float*)d_in[3];
  const float* Bb = (const float*)d_in[4];
  const float* eb = (const float*)d_in[5];
  float* Out = (float*)d_out;
  float* Alpha = Out + (size_t)TT * BSZN * EEN;  // output #1 region, also staging for p_choose

  k_prep_w<<<dim3(512), dim3(256), 0, stream>>>(W);
  k_prep_v<<<dim3(BHN * 16), dim3(256), 0, stream>>>(V);
  k_energy<<<dim3(BHN * 64), dim3(256), 0, stream>>>(Q, K, eb, Alpha);
  k_scan<<<dim3(BHN), dim3(256), 0, stream>>>(Alpha);
  k_av<<<dim3(1024), dim3(256), 0, stream>>>();
  k_out<<<dim3(1024), dim3(256), 0, stream>>>(Bb, Out);
}